// Round 3
// baseline (867.614 us; speedup 1.0000x reference)
//
#include <hip/hip_runtime.h>
#include <hip/hip_bf16.h>

#define NROW 16384
#define NFEATC 512
#define NH1 256
#define NH2 128
#define NCLS 8

typedef __attribute__((ext_vector_type(8))) short short8;
typedef __attribute__((ext_vector_type(4))) float f32x4;

__device__ __forceinline__ ushort f2bf(float f) {
  union { float f; unsigned u; } v; v.f = f;
  unsigned r = v.u + 0x7FFFu + ((v.u >> 16) & 1u);
  return (ushort)(r >> 16);
}
__device__ __forceinline__ float bf2f(ushort h) {
  union { unsigned u; float f; } v; v.u = ((unsigned)h) << 16; return v.f;
}

// in [K][N] fp32 -> out [N][K] bf16
__global__ __launch_bounds__(256) void transpose_conv(
    const float* __restrict__ in, ushort* __restrict__ out, int K, int N) {
  int idx = blockIdx.x * 256 + threadIdx.x;
  if (idx < K * N) {
    int k = idx / N, n = idx % N;
    out[(size_t)n * K + k] = f2bf(in[idx]);
  }
}

// C = A[M][K] @ BT[N][K]^T, 2-deep reg prefetch + LDS double buffer, BK=64, 4 waves.
// OUTM==1: Out bf16 [N][M]. OUTM==2: Out fp32 partial [ksl][M][N].
// If adjBF != nullptr (requires AFP32): n_blk==0 blocks also store the bf16
// conversion of their A panel to adjBF (same layout as A).
// KREV: iterate K descending within this block's range (L3 reuse across passes).
template<int BM, int BN, int WM, int WN, int KSPLIT, bool AFP32, int OUTM, bool KREV, int MINW>
__global__ __launch_bounds__(256, MINW) void gemm_pipe(
    const void* __restrict__ Ap, const ushort* __restrict__ BT,
    void* __restrict__ Outp, ushort* __restrict__ adjBF,
    const int nm, const int nn, const int M, const int N, const int K)
{
  constexpr int BK = 64, LDSK = BK + 8;
  constexpr int MR = WM / 16, NR = WN / 16;
  constexpr int nWc = BN / WN;
  static_assert((BM / WM) * (BN / WN) == 4, "4 waves");
  constexpr int AELEM = BM * BK / 256, ATPR = BK / AELEM;
  constexpr int BELEM = BN * BK / 256, BTPR = BK / BELEM;
  constexpr int A4s = AFP32 ? AELEM / 4 : 1;
  constexpr int A8s = AFP32 ? 1 : AELEM / 8;
  constexpr int B8s = (BELEM >= 8) ? BELEM / 8 : 1;

  __shared__ ushort As[2][BM * LDSK];
  __shared__ ushort Bs[2][BN * LDSK];

  const int t = threadIdx.x, l = t & 63, wid = t >> 6;
  const int wr0 = (wid / nWc) * WM, wc0 = (wid % nWc) * WN;

  // bijective XCD swizzle (gridDim.x % 8 == 0), n fastest
  const int cpx = gridDim.x >> 3;
  const int flat = (blockIdx.x & 7) * cpx + (blockIdx.x >> 3);
  const int n_blk = flat % nn;
  const int m_blk = (flat / nn) % nm;
  const int ksl = flat / (nn * nm);
  const int bm0 = m_blk * BM, bn0 = n_blk * BN;
  const int kper = K / KSPLIT, kbase = ksl * kper;
  const int NT = kper / BK;   // always even here

  const int ar = t / ATPR, ak = (t % ATPR) * AELEM;
  const int br = t / BTPR, bk = (t % BTPR) * BELEM;

  const float*  Af = (const float*)Ap + (size_t)(bm0 + ar) * K + kbase + ak;
  const ushort* Ab = (const ushort*)Ap + (size_t)(bm0 + ar) * K + kbase + ak;
  const ushort* Bp = BT + (size_t)(bn0 + br) * K + kbase + bk;
  ushort* adjW = adjBF ? (adjBF + (size_t)(bm0 + ar) * K + kbase + ak) : nullptr;
  const bool wbf = AFP32 && (adjW != nullptr) && (n_blk == 0);

  f32x4 acc[MR][NR] = {};

  auto loadRegs = [&](float4 (&aF)[A4s], short8 (&aB)[A8s],
                      short8 (&bV)[B8s], ushort4& b4, int it) {
    const int ko = (KREV ? (NT - 1 - it) : it) * BK;
    if constexpr (AFP32) {
      #pragma unroll
      for (int c = 0; c < A4s; c++) aF[c] = *(const float4*)(Af + ko + 4 * c);
    } else {
      #pragma unroll
      for (int c = 0; c < A8s; c++) aB[c] = *(const short8*)(Ab + ko + 8 * c);
    }
    if constexpr (BELEM >= 8) {
      #pragma unroll
      for (int c = 0; c < B8s; c++) bV[c] = *(const short8*)(Bp + ko + 8 * c);
    } else {
      b4 = *(const ushort4*)(Bp + ko);
    }
  };

  auto writeLds = [&](int buf, float4 (&aF)[A4s], short8 (&aB)[A8s],
                      short8 (&bV)[B8s], ushort4& b4, int it) {
    const int ko = (KREV ? (NT - 1 - it) : it) * BK;
    if constexpr (AFP32) {
      #pragma unroll
      for (int c = 0; c < A4s; c++) {
        ushort4 v;
        v.x = f2bf(aF[c].x); v.y = f2bf(aF[c].y);
        v.z = f2bf(aF[c].z); v.w = f2bf(aF[c].w);
        *(ushort4*)&As[buf][ar * LDSK + ak + 4 * c] = v;
        if (wbf) *(ushort4*)(adjW + ko + 4 * c) = v;
      }
    } else {
      #pragma unroll
      for (int c = 0; c < A8s; c++)
        *(short8*)&As[buf][ar * LDSK + ak + 8 * c] = aB[c];
    }
    if constexpr (BELEM >= 8) {
      #pragma unroll
      for (int c = 0; c < B8s; c++)
        *(short8*)&Bs[buf][br * LDSK + bk + 8 * c] = bV[c];
    } else {
      *(ushort4*)&Bs[buf][br * LDSK + bk] = b4;
    }
  };

  auto compute = [&](int buf) {
    const int rr = l & 15;
    #pragma unroll
    for (int kk = 0; kk < 2; kk++) {
      const int kb = kk * 32 + (l >> 4) * 8;
      short8 af[MR], bfv[NR];
      #pragma unroll
      for (int m = 0; m < MR; m++)
        af[m] = *(short8*)&As[buf][(wr0 + m * 16 + rr) * LDSK + kb];
      #pragma unroll
      for (int n = 0; n < NR; n++)
        bfv[n] = *(short8*)&Bs[buf][(wc0 + n * 16 + rr) * LDSK + kb];
      #pragma unroll
      for (int m = 0; m < MR; m++)
        #pragma unroll
        for (int n = 0; n < NR; n++)
          acc[m][n] = __builtin_amdgcn_mfma_f32_16x16x32_bf16(af[m], bfv[n], acc[m][n], 0, 0, 0);
    }
  };

  // two register sets, 2-deep prefetch
  float4 XaF[A4s], YaF[A4s];
  short8 XaB[A8s], YaB[A8s];
  short8 XbV[B8s], YbV[B8s];
  ushort4 Xb4, Yb4;

  loadRegs(XaF, XaB, XbV, Xb4, 0);
  writeLds(0, XaF, XaB, XbV, Xb4, 0);
  loadRegs(XaF, XaB, XbV, Xb4, 1);   // X now holds step 1
  __syncthreads();

  for (int it = 0; it < NT; it += 2) {
    if (it + 2 < NT) loadRegs(YaF, YaB, YbV, Yb4, it + 2);
    compute(0);                                         // step it
    if (it + 1 < NT) writeLds(1, XaF, XaB, XbV, Xb4, it + 1);
    __syncthreads();
    if (it + 3 < NT) loadRegs(XaF, XaB, XbV, Xb4, it + 3);
    if (it + 1 < NT) compute(1);                        // step it+1
    if (it + 2 < NT) writeLds(0, YaF, YaB, YbV, Yb4, it + 2);
    __syncthreads();
  }

  #pragma unroll
  for (int m = 0; m < MR; m++) {
    const int row = bm0 + wr0 + m * 16 + (l >> 4) * 4;
    #pragma unroll
    for (int n = 0; n < NR; n++) {
      const int col = bn0 + wc0 + n * 16 + (l & 15);
      if constexpr (OUTM == 1) {
        ushort4 v;
        v.x = f2bf(acc[m][n][0]); v.y = f2bf(acc[m][n][1]);
        v.z = f2bf(acc[m][n][2]); v.w = f2bf(acc[m][n][3]);
        *(ushort4*)((ushort*)Outp + (size_t)col * M + row) = v;
      } else {
        float* o = (float*)Outp + (size_t)ksl * M * N;
        #pragma unroll
        for (int r = 0; r < 4; r++)
          o[(size_t)(row + r) * N + col] = acc[m][n][r];
      }
    }
  }
}

// out[M][N] bf16 = relu(sum_k part[k][M][N] + bias[col]); vectorized by 4
__global__ __launch_bounds__(256) void reduce_relu(
    const float* __restrict__ part, const float* __restrict__ bias,
    ushort* __restrict__ out, const int MN, const int N, const int KS) {
  const int i4 = (blockIdx.x * 256 + threadIdx.x) * 4;
  if (i4 >= MN) return;
  float4 s = *(const float4*)(part + i4);
  for (int k = 1; k < KS; k++) {
    float4 p = *(const float4*)(part + (size_t)k * MN + i4);
    s.x += p.x; s.y += p.y; s.z += p.z; s.w += p.w;
  }
  const int col = i4 % N;
  float4 b = *(const float4*)(bias + col);
  ushort4 v;
  v.x = f2bf(fmaxf(s.x + b.x, 0.0f));
  v.y = f2bf(fmaxf(s.y + b.y, 0.0f));
  v.z = f2bf(fmaxf(s.z + b.z, 0.0f));
  v.w = f2bf(fmaxf(s.w + b.w, 0.0f));
  *(ushort4*)(out + i4) = v;
}

// s3T[16][NROW] bf16 = (h2 @ W3)^T, rows 8..15 zero-padded
__global__ __launch_bounds__(256) void mm_small(
    const ushort* __restrict__ h2, const float* __restrict__ W3,
    ushort* __restrict__ s3T) {
  __shared__ float w[NH2 * NCLS];
  for (int i = threadIdx.x; i < NH2 * NCLS; i += 256) w[i] = W3[i];
  __syncthreads();
  const int m = blockIdx.x * 256 + threadIdx.x;
  float acc[8] = {};
  const ushort* row = h2 + (size_t)m * NH2;
  #pragma unroll
  for (int c = 0; c < NH2 / 8; c++) {
    short8 v = *(const short8*)(row + c * 8);
    #pragma unroll
    for (int j = 0; j < 8; j++) {
      float h = bf2f((ushort)v[j]);
      const int k = c * 8 + j;
      #pragma unroll
      for (int n = 0; n < 8; n++) acc[n] += h * w[k * 8 + n];
    }
  }
  #pragma unroll
  for (int n = 0; n < 8; n++) s3T[(size_t)n * NROW + m] = f2bf(acc[n]);
  #pragma unroll
  for (int n = 8; n < 16; n++) s3T[(size_t)n * NROW + m] = 0;
}

// out[NROW][8] = log_softmax(sum_ksl part + b3)
__global__ __launch_bounds__(256) void final_reduce(
    const float* __restrict__ part, const float* __restrict__ b3,
    float* __restrict__ out) {
  const int m = blockIdx.x * 256 + threadIdx.x;
  float4 s0 = make_float4(0, 0, 0, 0), s1 = make_float4(0, 0, 0, 0);
  #pragma unroll
  for (int k = 0; k < 4; k++) {
    const float4* p = (const float4*)(part + ((size_t)k * NROW + m) * 16);
    float4 a = p[0], b = p[1];
    s0.x += a.x; s0.y += a.y; s0.z += a.z; s0.w += a.w;
    s1.x += b.x; s1.y += b.y; s1.z += b.z; s1.w += b.w;
  }
  float v[8];
  v[0] = s0.x + b3[0]; v[1] = s0.y + b3[1]; v[2] = s0.z + b3[2]; v[3] = s0.w + b3[3];
  v[4] = s1.x + b3[4]; v[5] = s1.y + b3[5]; v[6] = s1.z + b3[6]; v[7] = s1.w + b3[7];
  float mx = v[0];
  #pragma unroll
  for (int n = 1; n < 8; n++) mx = fmaxf(mx, v[n]);
  float s = 0.0f;
  #pragma unroll
  for (int n = 0; n < 8; n++) s += expf(v[n] - mx);
  const float lse = logf(s) + mx;
  float4* o = (float4*)(out + (size_t)m * 8);
  o[0] = make_float4(v[0] - lse, v[1] - lse, v[2] - lse, v[3] - lse);
  o[1] = make_float4(v[4] - lse, v[5] - lse, v[6] - lse, v[7] - lse);
}

extern "C" void kernel_launch(void* const* d_in, const int* in_sizes, int n_in,
                              void* d_out, int out_size, void* d_ws, size_t ws_size,
                              hipStream_t stream) {
  const float* x   = (const float*)d_in[0];
  const float* adj = (const float*)d_in[1];
  const float* W1  = (const float*)d_in[2];
  const float* b1  = (const float*)d_in[3];
  const float* W2  = (const float*)d_in[4];
  const float* b2  = (const float*)d_in[5];
  const float* W3  = (const float*)d_in[6];
  const float* b3  = (const float*)d_in[7];
  float* out = (float*)d_out;

  char* ws = (char*)d_ws;
  size_t off = 0;
  ushort* W1T = (ushort*)(ws + off); off += (size_t)NH1 * NFEATC * 2;    // 256 KB
  ushort* W2T = (ushort*)(ws + off); off += (size_t)NH2 * NH1 * 2;      // 64 KB
  ushort* s1T = (ushort*)(ws + off); off += (size_t)NH1 * NROW * 2;     // 8 MiB
  ushort* h1  = (ushort*)(ws + off); off += (size_t)NROW * NH1 * 2;     // 8 MiB
  ushort* s2T = (ushort*)(ws + off); off += (size_t)NH2 * NROW * 2;     // 4 MiB
  ushort* h2  = (ushort*)(ws + off); off += (size_t)NROW * NH2 * 2;     // 4 MiB
  ushort* s3T = (ushort*)(ws + off); off += (size_t)16 * NROW * 2;      // 512 KB
  float*  part = (float*)(ws + off); off += (size_t)2 * NROW * NH1 * 4; // 32 MiB
  ushort* adjBF = (ushort*)(ws + off); off += (size_t)NROW * NROW * 2;  // 512 MiB

  transpose_conv<<<(NFEATC * NH1 + 255) / 256, 256, 0, stream>>>(W1, W1T, NFEATC, NH1);
  transpose_conv<<<(NH1 * NH2 + 255) / 256, 256, 0, stream>>>(W2, W2T, NH1, NH2);

  // s1T[256][16384] = (x @ W1)^T
  gemm_pipe<64, 128, 32, 64, 1, true, 1, false, 2><<<512, 256, 0, stream>>>(
      x, W1T, s1T, nullptr, 256, 2, NROW, NH1, NFEATC);
  // part[2][16384][256] = adj @ s1 (split-K=2); n_blk==0 also writes adjBF
  gemm_pipe<128, 128, 64, 64, 2, true, 2, false, 2><<<512, 256, 0, stream>>>(
      adj, s1T, part, adjBF, 128, 2, NROW, NH1, NROW);
  // h1 = relu(sum part + b1)
  reduce_relu<<<(NROW * NH1 / 4 + 255) / 256, 256, 0, stream>>>(
      part, b1, h1, NROW * NH1, NH1, 2);
  // s2T[128][16384] = (h1 @ W2)^T
  gemm_pipe<64, 128, 32, 64, 1, false, 1, false, 2><<<256, 256, 0, stream>>>(
      h1, W2T, s2T, nullptr, 256, 1, NROW, NH2, NH1);
  // part[4][16384][128] = adjBF @ s2 (split-K=4, K descending for L3 reuse)
  gemm_pipe<128, 128, 64, 64, 4, false, 2, true, 2><<<512, 256, 0, stream>>>(
      adjBF, s2T, part, nullptr, 128, 1, NROW, NH2, NROW);
  // h2 = relu(sum part + b2)
  reduce_relu<<<(NROW * NH2 / 4 + 255) / 256, 256, 0, stream>>>(
      part, b2, h2, NROW * NH2, NH2, 4);
  // s3T[16][16384] = (h2 @ W3)^T (bf16, zero-padded to 16 rows)
  mm_small<<<NROW / 256, 256, 0, stream>>>(h2, W3, s3T);
  // part[4][16384][16] = adjBF @ s3 (split-K=4)
  gemm_pipe<128, 16, 32, 16, 4, false, 2, false, 3><<<512, 256, 0, stream>>>(
      adjBF, s3T, part, nullptr, 128, 1, NROW, 16, NROW);
  // out = log_softmax(sum part + b3)
  final_reduce<<<NROW / 256, 256, 0, stream>>>(part, b3, out);
}